// Round 3
// baseline (262.703 us; speedup 1.0000x reference)
//
#include <hip/hip_runtime.h>

#define OUT_N 11008
#define IN_K  4096
#define BATCH 32
#define SEGS  8
#define KSEG  (IN_K / SEGS)     // 512 k per block
#define OPB   64                // outputs per block (4 waves x 16)
#define XSTRIDE 520             // KSEG + 8 pad (bf16 elems)

typedef __attribute__((ext_vector_type(8))) short short8;
typedef __attribute__((ext_vector_type(4))) float float4v;

// out[b][o] = bias[o]; main kernel atomically accumulates K-segment partials.
__global__ __launch_bounds__(256) void init_kernel(
    const float* __restrict__ bias, float* __restrict__ out)
{
    int i = blockIdx.x * 256 + threadIdx.x;
    if (i < BATCH * OUT_N) out[i] = bias[i % OUT_N];
}

// fp32 -> bf16 RNE, bit pattern as ushort
__device__ __forceinline__ unsigned short f2bf(float f) {
    unsigned u = __builtin_bit_cast(unsigned, f);
    unsigned r = u + 0x7FFFu + ((u >> 16) & 1u);
    return (unsigned short)(r >> 16);
}

// pack two fp32 (exact {-1,0,1}) into two bf16 by mantissa truncation:
// dst = { hi16(fhi), hi16(flo) }
__device__ __forceinline__ unsigned pkbf16(float fhi, float flo) {
    return __builtin_amdgcn_perm(__builtin_bit_cast(unsigned, fhi),
                                 __builtin_bit_cast(unsigned, flo),
                                 0x07060302u);
}

// Wave owns 16 outputs x 32 batch (2 MFMA acc tiles); block = 4 waves = 64
// outputs x K-slice of 512. Weights stream global->VGPR with 2-deep
// software-pipelined prefetch (4 dwordx4 in flight per wave minimum);
// x is converted fp32->bf16 during LDS staging (L3-resident, ~free).
__global__ __launch_bounds__(256, 4) void lin2bit_kernel(
    const int* __restrict__ wq, const float* __restrict__ scale,
    const float* __restrict__ x, float* __restrict__ out)
{
    __shared__ unsigned short xs[BATCH][XSTRIDE];   // 33280 B -> 4 blocks/CU

    const int t    = threadIdx.x;
    const int lane = t & 63;
    const int wave = t >> 6;
    const int kseg = blockIdx.y * KSEG;

    // Stage x[0:32][kseg:kseg+512] -> LDS as bf16. 16 float4 per thread,
    // coalesced reads; ds_write_b64 2-way (free).
#pragma unroll
    for (int it = 0; it < 16; ++it) {
        int idx = it * 256 + t;
        int b   = idx >> 7;            // 128 float4 per row
        int k4  = idx & 127;
        float4 v = *reinterpret_cast<const float4*>(x + b * IN_K + kseg + k4 * 4);
        ushort4 h = { f2bf(v.x), f2bf(v.y), f2bf(v.z), f2bf(v.w) };
        *reinterpret_cast<ushort4*>(&xs[b][k4 * 4]) = h;
    }
    __syncthreads();

    const int quad = lane >> 4;
    const int l16  = lane & 15;
    const int o    = blockIdx.x * OPB + wave * 16 + l16;

    const int* __restrict__ wp = wq + (size_t)o * IN_K + kseg + quad * 8;
    const unsigned short* xrow0 = &xs[l16][quad * 8];
    const unsigned short* xrow1 = &xs[l16 + 16][quad * 8];

    float4v acc0 = {0.f, 0.f, 0.f, 0.f};
    float4v acc1 = {0.f, 0.f, 0.f, 0.f};

    // prefetch registers for one 64-k macro-iter (4 x dwordx4)
    int4 p0 = *reinterpret_cast<const int4*>(wp);
    int4 p1 = *reinterpret_cast<const int4*>(wp + 4);
    int4 p2 = *reinterpret_cast<const int4*>(wp + 32);
    int4 p3 = *reinterpret_cast<const int4*>(wp + 36);

#define COMPUTE64(kbase, c0, c1, c2, c3)                                      \
    do {                                                                      \
        uint4 bw0;                                                            \
        bw0.x = pkbf16((float)(c0).y, (float)(c0).x);                         \
        bw0.y = pkbf16((float)(c0).w, (float)(c0).z);                         \
        bw0.z = pkbf16((float)(c1).y, (float)(c1).x);                         \
        bw0.w = pkbf16((float)(c1).w, (float)(c1).z);                         \
        short8 bf0 = __builtin_bit_cast(short8, bw0);                         \
        short8 a0 = *reinterpret_cast<const short8*>(xrow0 + (kbase));        \
        short8 a1 = *reinterpret_cast<const short8*>(xrow1 + (kbase));        \
        acc0 = __builtin_amdgcn_mfma_f32_16x16x32_bf16(a0, bf0, acc0, 0,0,0); \
        acc1 = __builtin_amdgcn_mfma_f32_16x16x32_bf16(a1, bf0, acc1, 0,0,0); \
        uint4 bw1;                                                            \
        bw1.x = pkbf16((float)(c2).y, (float)(c2).x);                         \
        bw1.y = pkbf16((float)(c2).w, (float)(c2).z);                         \
        bw1.z = pkbf16((float)(c3).y, (float)(c3).x);                         \
        bw1.w = pkbf16((float)(c3).w, (float)(c3).z);                         \
        short8 bf1 = __builtin_bit_cast(short8, bw1);                         \
        short8 a2 = *reinterpret_cast<const short8*>(xrow0 + (kbase) + 32);   \
        short8 a3 = *reinterpret_cast<const short8*>(xrow1 + (kbase) + 32);   \
        acc0 = __builtin_amdgcn_mfma_f32_16x16x32_bf16(a2, bf1, acc0, 0,0,0); \
        acc1 = __builtin_amdgcn_mfma_f32_16x16x32_bf16(a3, bf1, acc1, 0,0,0); \
    } while (0)

#pragma unroll
    for (int ki = 0; ki < KSEG - 64; ki += 64) {
        int4 c0 = p0, c1 = p1, c2 = p2, c3 = p3;
        // issue next macro-iter's loads before consuming current
        p0 = *reinterpret_cast<const int4*>(wp + ki + 64);
        p1 = *reinterpret_cast<const int4*>(wp + ki + 68);
        p2 = *reinterpret_cast<const int4*>(wp + ki + 96);
        p3 = *reinterpret_cast<const int4*>(wp + ki + 100);
        COMPUTE64(ki, c0, c1, c2, c3);
    }
    COMPUTE64(KSEG - 64, p0, p1, p2, p3);
#undef COMPUTE64

    // C/D layout: col(o) = lane&15, row(b) = quad*4 + reg
    const float s = scale[o];
    const int b0 = quad * 4;
#pragma unroll
    for (int r = 0; r < 4; ++r) {
        unsafeAtomicAdd(out + (size_t)(b0 + r)      * OUT_N + o, s * acc0[r]);
        unsafeAtomicAdd(out + (size_t)(b0 + r + 16) * OUT_N + o, s * acc1[r]);
    }
}

extern "C" void kernel_launch(void* const* d_in, const int* in_sizes, int n_in,
                              void* d_out, int out_size, void* d_ws, size_t ws_size,
                              hipStream_t stream) {
    const float* x     = (const float*)d_in[0];
    const int*   wq    = (const int*)d_in[1];
    const float* scale = (const float*)d_in[2];
    const float* bias  = (const float*)d_in[3];
    float* out = (float*)d_out;

    init_kernel<<<dim3((BATCH * OUT_N + 255) / 256), 256, 0, stream>>>(bias, out);
    lin2bit_kernel<<<dim3(OUT_N / OPB, SEGS), 256, 0, stream>>>(wq, scale, x, out);
}

// Round 4
// 255.813 us; speedup vs baseline: 1.0269x; 1.0269x over previous
//
#include <hip/hip_runtime.h>

#define OUT_N 11008
#define IN_K  4096
#define BATCH 32
#define SEGS  16
#define KSEG  (IN_K / SEGS)     // 256 k per block
#define OPB   64                // outputs per block (4 waves x 16 rows)
#define WSTR  (KSEG + 8)        // padded LDS row stride (bf16 elems)

typedef __attribute__((ext_vector_type(8))) short short8;
typedef __attribute__((ext_vector_type(4))) float float4v;

// out[b][o] = bias[o]; main kernel atomically accumulates K-segment partials.
__global__ __launch_bounds__(256) void init_kernel(
    const float* __restrict__ bias, float* __restrict__ out)
{
    int i = blockIdx.x * 256 + threadIdx.x;
    if (i < BATCH * OUT_N) out[i] = bias[i % OUT_N];
}

// fp32 -> bf16 RNE
__device__ __forceinline__ unsigned short f2bf(float f) {
    unsigned u = __builtin_bit_cast(unsigned, f);
    unsigned r = u + 0x7FFFu + ((u >> 16) & 1u);
    return (unsigned short)(r >> 16);
}

// pack two fp32 (exact {-1,0,1}) into two bf16 by mantissa truncation:
// dst = { hi16(fhi), hi16(flo) }
__device__ __forceinline__ unsigned pkbf16(float fhi, float flo) {
    return __builtin_amdgcn_perm(__builtin_bit_cast(unsigned, fhi),
                                 __builtin_bit_cast(unsigned, flo),
                                 0x07060302u);
}

// Block = 4 waves = 64 output rows x KSEG=256 k. Weight staging: wave w owns
// rows [w*16, w*16+16); per row one wave-instruction reads 64 lanes x int4
// = 1 KB CONTIGUOUS global (max TA-coalescing), converts to bf16, ds_write_b64
// into padded row-major LDS. Compute: MFMA 16x16x32, B-frags via ds_read_b128
// (row stride 528 B == 4 words mod 32 -> balanced bank aliasing).
__global__ __launch_bounds__(256, 2) void lin2bit_kernel(
    const int* __restrict__ wq, const float* __restrict__ scale,
    const float* __restrict__ x, float* __restrict__ out)
{
    __shared__ unsigned short wl[OPB][WSTR];    // 64x264x2 = 33792 B
    __shared__ unsigned short xs[BATCH][WSTR];  // 32x264x2 = 16896 B -> 3 blk/CU

    const int t    = threadIdx.x;
    const int lane = t & 63;
    const int wave = t >> 6;
    const int kseg = blockIdx.y * KSEG;
    const int o0   = blockIdx.x * OPB;

    // --- stage x[0:32][kseg:+256] fp32 -> bf16 LDS (all 256 threads) ---
#pragma unroll
    for (int it = 0; it < 8; ++it) {
        int idx = it * 256 + t;
        int b   = idx >> 6;            // 64 float4 per row
        int k4  = idx & 63;
        float4 v = *reinterpret_cast<const float4*>(x + b * IN_K + kseg + k4 * 4);
        ushort4 h = { f2bf(v.x), f2bf(v.y), f2bf(v.z), f2bf(v.w) };
        *reinterpret_cast<ushort4*>(&xs[b][k4 * 4]) = h;
    }

    // --- stage W rows: wave w -> rows w*16..w*16+15, 1 KB contiguous/row ---
#pragma unroll
    for (int r = 0; r < 16; ++r) {
        const int rl = wave * 16 + r;
        const int4 v = *reinterpret_cast<const int4*>(
            wq + (size_t)(o0 + rl) * IN_K + kseg + lane * 4);
        unsigned lo = pkbf16((float)v.y, (float)v.x);
        unsigned hi = pkbf16((float)v.w, (float)v.z);
        uint2 p = { lo, hi };
        *reinterpret_cast<uint2*>(&wl[rl][lane * 4]) = p;
    }
    __syncthreads();

    // --- compute: wave w owns outputs o0 + w*16 + l16, batches via 2 tiles ---
    const int quad = lane >> 4;
    const int l16  = lane & 15;
    const int o    = o0 + wave * 16 + l16;

    const unsigned short* wrow = &wl[wave * 16 + l16][quad * 8];
    const unsigned short* xrow0 = &xs[l16][quad * 8];
    const unsigned short* xrow1 = &xs[l16 + 16][quad * 8];

    float4v acc0 = {0.f, 0.f, 0.f, 0.f};
    float4v acc1 = {0.f, 0.f, 0.f, 0.f};

#pragma unroll
    for (int kt = 0; kt < KSEG / 32; ++kt) {
        short8 bfrag = *reinterpret_cast<const short8*>(wrow + kt * 32);
        short8 a0    = *reinterpret_cast<const short8*>(xrow0 + kt * 32);
        short8 a1    = *reinterpret_cast<const short8*>(xrow1 + kt * 32);
        acc0 = __builtin_amdgcn_mfma_f32_16x16x32_bf16(a0, bfrag, acc0, 0, 0, 0);
        acc1 = __builtin_amdgcn_mfma_f32_16x16x32_bf16(a1, bfrag, acc1, 0, 0, 0);
    }

    // C/D layout: col(o) = lane&15, row(b) = quad*4 + reg
    const float s = scale[o];
    const int b0 = quad * 4;
#pragma unroll
    for (int r = 0; r < 4; ++r) {
        unsafeAtomicAdd(out + (size_t)(b0 + r)      * OUT_N + o, s * acc0[r]);
        unsafeAtomicAdd(out + (size_t)(b0 + r + 16) * OUT_N + o, s * acc1[r]);
    }
}

extern "C" void kernel_launch(void* const* d_in, const int* in_sizes, int n_in,
                              void* d_out, int out_size, void* d_ws, size_t ws_size,
                              hipStream_t stream) {
    const float* x     = (const float*)d_in[0];
    const int*   wq    = (const int*)d_in[1];
    const float* scale = (const float*)d_in[2];
    const float* bias  = (const float*)d_in[3];
    float* out = (float*)d_out;

    init_kernel<<<dim3((BATCH * OUT_N + 255) / 256), 256, 0, stream>>>(bias, out);
    lin2bit_kernel<<<dim3(OUT_N / OPB, SEGS), 256, 0, stream>>>(wq, scale, x, out);
}